// Round 6
// baseline (396.733 us; speedup 1.0000x reference)
//
#include <hip/hip_runtime.h>

// SpatialAttention: x[4,4096,1024] fp32, F=16 -> 64 frames x 256 patches,
// H=16 heads, D=64.  Pipeline: cvt->bf16, QKV GEMM (256^2 8-phase bf16
// MFMA), per-(bf,h) attention, out-proj GEMM (fp32 out).

typedef __bf16 bf16x8 __attribute__((ext_vector_type(8)));
typedef float f32x4 __attribute__((ext_vector_type(4)));

__device__ __forceinline__ void gload_lds16(const void* g, void* l) {
  __builtin_amdgcn_global_load_lds(
      (__attribute__((address_space(1))) void*)(g),
      (__attribute__((address_space(3))) void*)(l), 16, 0, 0);
}

#define VMW(N) asm volatile("s_waitcnt vmcnt(" #N ")" ::: "memory")

// ---------------- fp32 -> bf16 conversion (vectorized, 8 elems/thread) ----
__global__ __launch_bounds__(256) void cvt_f32_bf16(
    const float* __restrict__ in, __bf16* __restrict__ out, int n8) {
  int i = blockIdx.x * 256 + threadIdx.x;
  if (i >= n8) return;
  const float4* p = (const float4*)in;
  float4 a = p[2 * i];
  float4 b = p[2 * i + 1];
  bf16x8 v;
  v[0] = (__bf16)a.x; v[1] = (__bf16)a.y; v[2] = (__bf16)a.z; v[3] = (__bf16)a.w;
  v[4] = (__bf16)b.x; v[5] = (__bf16)b.y; v[6] = (__bf16)b.z; v[7] = (__bf16)b.w;
  ((bf16x8*)out)[i] = v;
}

// ---------------- GEMM 256x256, 8-phase pipelined, BK=64 -------------------
// C[M,N] = A[M,K]*B[N,K]^T + bias.  8 waves (2Mx4N), each owns 128x64 out.
// LDS: per K-tile, A and B each split into K-halves [256 rows][32 K] (16 KB);
// double-buffered -> 128 KB.  Each phase: ds_read subtile + stage ONE
// half-tile (2 gload_lds/thread) + barrier + lgkm(0) + 16 MFMA + [vmcnt(10)]
// + barrier.  5 half-tiles in flight; vmcnt never drains to 0 mid-loop.
// Swizzle: 16B-block p at row r holds logical block p ^ ((r>>2)&3), applied
// on the pre-swizzled GLOBAL source (linear DMA dest) and on ds_read addr.
template <bool BF16_OUT>
__global__ __launch_bounds__(512, 2) void gemm256(
    const __bf16* __restrict__ A, const __bf16* __restrict__ Bm,
    const float* __restrict__ bias, void* __restrict__ Cv,
    int M, int N, int K) {
  __shared__ alignas(16) __bf16 Asl[2][2][256 * 32];  // [buf][kk-half] 64 KB
  __shared__ alignas(16) __bf16 Bsl[2][2][256 * 32];  // 64 KB

  const int tid = threadIdx.x, lane = tid & 63, wid = tid >> 6;
  const int wr = wid >> 2, wc = wid & 3;  // 2 x 4 waves
  const int l15 = lane & 15, l4 = lane >> 4;

  // XCD-aware bijective swizzle (grids here are multiples of 8)
  const int nwg = gridDim.x * gridDim.y;
  const int bid = blockIdx.y * gridDim.x + blockIdx.x;
  const int swz = (bid & 7) * (nwg >> 3) + (bid >> 3);
  const int bn = swz % gridDim.x, bm = swz / gridDim.x;

  const int NT = K >> 6;  // K-tiles of 64 (even; NT>=4)

  // ---- staging: half-tile = 256 rows x 32 K = 1024 segs of 16B; thread
  // covers segs {tid, 512+tid}.  row = seg>>2, phys blk p = seg&3 holds
  // logical blk p ^ ((row>>2)&3)  (c=1 adds 128 rows: (row>>2)+32, &3 same).
  const int srow = tid >> 2;
  const int sblk = (tid & 3) ^ ((srow >> 2) & 3);
  const __bf16* sA = A + (size_t)(bm * 256 + srow) * K + sblk * 8;
  const __bf16* sB = Bm + (size_t)(bn * 256 + srow) * K + sblk * 8;
  const size_t rs128 = (size_t)128 * K;

#define STG(MATP, DST, kOff)                              \
  {                                                       \
    gload_lds16(MATP + (kOff), &(DST)[tid * 8]);          \
    gload_lds16(MATP + rs128 + (kOff), &(DST)[4096 + tid * 8]); \
  }

  // ---- ds_read offsets: frag row r, elem = r*32 + ((l4^((r>>2)&3))*8).
  // For r = base16 + l15 the swizzle reduces to l4 ^ (l15>>2): base-free.
  const int pk = ((l4 ^ (l15 >> 2)) & 3) * 8;
  const int raOff = (wr * 128 + l15) * 32 + pk;  // + m*512
  const int rbOff = (wc * 64 + l15) * 32 + pk;   // + f*512

  f32x4 acc[8][4] = {};
  bf16x8 a_[8];
  bf16x8 b_[4];

  // phase body: reads (A if CH==0, B frags CH*2..CH*2+1), stage, barrier,
  // lgkm0, 16 MFMA, gate, barrier.
#define PH(BUF, KK, CH, STAGE_STMT, GATE_STMT)                        \
  {                                                                   \
    const __bf16* Ab = &Asl[BUF][KK][0];                              \
    const __bf16* Bb = &Bsl[BUF][KK][0];                              \
    if (CH == 0) {                                                    \
      _Pragma("unroll") for (int m = 0; m < 8; ++m)                   \
          a_[m] = *(const bf16x8*)(Ab + raOff + m * 512);             \
    }                                                                 \
    b_[CH * 2 + 0] = *(const bf16x8*)(Bb + rbOff + (CH * 2 + 0) * 512); \
    b_[CH * 2 + 1] = *(const bf16x8*)(Bb + rbOff + (CH * 2 + 1) * 512); \
    STAGE_STMT;                                                       \
    __builtin_amdgcn_s_barrier();                                     \
    asm volatile("s_waitcnt lgkmcnt(0)" ::: "memory");                \
    __builtin_amdgcn_sched_barrier(0);                                \
    __builtin_amdgcn_s_setprio(1);                                    \
    _Pragma("unroll") for (int m = 0; m < 8; ++m) {                   \
      acc[m][CH * 2 + 0] = __builtin_amdgcn_mfma_f32_16x16x32_bf16(   \
          a_[m], b_[CH * 2 + 0], acc[m][CH * 2 + 0], 0, 0, 0);        \
      acc[m][CH * 2 + 1] = __builtin_amdgcn_mfma_f32_16x16x32_bf16(   \
          a_[m], b_[CH * 2 + 1], acc[m][CH * 2 + 1], 0, 0, 0);        \
    }                                                                 \
    __builtin_amdgcn_s_setprio(0);                                    \
    GATE_STMT;                                                        \
    __builtin_amdgcn_s_barrier();                                     \
  }

  // ---- prologue: 7 half-tiles in steady-state slot order (14 loads);
  // 8th (Bh1 of tile1) is staged by iter0-ph1.
  STG(sA, Asl[0][0], 0);    // tile0 Ah0
  STG(sB, Bsl[0][0], 0);    // tile0 Bh0
  STG(sA, Asl[0][1], 32);   // tile0 Ah1
  STG(sB, Bsl[0][1], 32);   // tile0 Bh1
  STG(sA, Asl[1][0], 64);   // tile1 Ah0
  STG(sB, Bsl[1][0], 64);   // tile1 Bh0
  STG(sA, Asl[1][1], 96);   // tile1 Ah1
  VMW(10);  // tile0 Ah0+Bh0 landed; 5 halves in flight
  __builtin_amdgcn_s_barrier();

  for (int t = 0; t < NT; t += 2) {
    const bool st2 = (t + 2 < NT);  // also == (t+3 < NT) for even NT
    // ph1: buf0 kk0 ch0 | stage Bh1(buf1) <- tile t+1 (always valid)
    PH(0, 0, 0, { STG(sB, Bsl[1][1], (t + 1) * 64 + 32); }, {});
    // ph2: buf0 kk0 ch1 | stage Ah0(buf0) <- t+2 | gate
    PH(0, 0, 1, { if (st2) STG(sA, Asl[0][0], (t + 2) * 64); },
       { if (st2) VMW(10); else VMW(8); });
    // ph3: buf0 kk1 ch0 | stage Bh0(buf0) <- t+2
    PH(0, 1, 0, { if (st2) STG(sB, Bsl[0][0], (t + 2) * 64); }, {});
    // ph4: buf0 kk1 ch1 | stage Ah1(buf0) <- t+2 | gate
    PH(0, 1, 1, { if (st2) STG(sA, Asl[0][1], (t + 2) * 64 + 32); },
       { if (st2) VMW(10); else VMW(4); });
    // ph5: buf1 kk0 ch0 | stage Bh1(buf0) <- t+2
    PH(1, 0, 0, { if (st2) STG(sB, Bsl[0][1], (t + 2) * 64 + 32); }, {});
    // ph6: buf1 kk0 ch1 | stage Ah0(buf1) <- t+3 | gate
    PH(1, 0, 1, { if (st2) STG(sA, Asl[1][0], (t + 3) * 64); },
       { if (st2) VMW(10); else VMW(0); });
    // ph7: buf1 kk1 ch0 | stage Bh0(buf1) <- t+3
    PH(1, 1, 0, { if (st2) STG(sB, Bsl[1][0], (t + 3) * 64); }, {});
    // ph8: buf1 kk1 ch1 | stage Ah1(buf1) <- t+3 | gate
    PH(1, 1, 1, { if (st2) STG(sA, Asl[1][1], (t + 3) * 64 + 32); },
       { if (st2) VMW(10); });
  }
#undef PH
#undef STG

  // ---- epilogue: D col=lane&15, row=(lane>>4)*4+r
  const int r0 = l4 * 4;
#pragma unroll
  for (int m = 0; m < 8; ++m) {
#pragma unroll
    for (int n = 0; n < 4; ++n) {
      int row = bm * 256 + wr * 128 + m * 16 + r0;
      int col = bn * 256 + wc * 64 + n * 16 + l15;
      float bb = bias[col];
#pragma unroll
      for (int r = 0; r < 4; ++r) {
        float v = acc[m][n][r] + bb;
        if (BF16_OUT)
          ((__bf16*)Cv)[(size_t)(row + r) * N + col] = (__bf16)v;
        else
          ((float*)Cv)[(size_t)(row + r) * N + col] = v;
      }
    }
  }
}

// ---------------- attention: one block per (bf, h) ------------------------
// qkv[16384][3072] bf16: q at col h*64, k at 1024+h*64, v at 2048+h*64.
// 4 waves x 64 q-rows; K,V (256x64) in LDS (K xor-swizzled, V transposed);
// online softmax over 8 j-tiles of 32.
__global__ __launch_bounds__(256, 2) void attn_kernel(
    const __bf16* __restrict__ qkv, __bf16* __restrict__ attnOut) {
  __shared__ alignas(16) __bf16 Ks[256 * 64];       // 32 KB, swizzled
  __shared__ alignas(16) __bf16 Vt[64 * 256];       // 32 KB, transposed+swz
  __shared__ alignas(16) __bf16 Pl[4][64 * 32];     // 16 KB, per-wave P tile

  const int h = blockIdx.x, bf = blockIdx.y;
  const int tid = threadIdx.x, lane = tid & 63, wid = tid >> 6;
  const int l15 = lane & 15, l4 = lane >> 4;

  const __bf16* base = qkv + (size_t)(bf * 256) * 3072 + h * 64;

  // --- stage K: pre-swizzled global source -> linear LDS write (rule 21)
#pragma unroll
  for (int rr = 0; rr < 8; ++rr) {
    int s = rr * 256 + wid * 64 + lane;
    int r = s >> 3, t = s & 7, c8 = t ^ (r & 7);
    gload_lds16(base + 1024 + (size_t)r * 3072 + c8 * 8, &Ks[s * 8]);
  }

  // --- stage V transposed: thread t owns global row j=t (64 elems)
  {
    const __bf16* vrow = base + 2048 + (size_t)tid * 3072;
    bf16x8 vv[8];
#pragma unroll
    for (int b8 = 0; b8 < 8; ++b8) vv[b8] = *(const bf16x8*)(vrow + b8 * 8);
#pragma unroll
    for (int b8 = 0; b8 < 8; ++b8)
#pragma unroll
      for (int e = 0; e < 8; ++e) {
        int d = b8 * 8 + e;
        Vt[d * 256 + (((tid >> 3) ^ (d & 7)) * 8) + (tid & 7)] = vv[b8][e];
      }
  }

  // --- Q fragments (A-operand: row=lane&15, k=(lane>>4)*8+j), direct global
  bf16x8 aq[4][2];
  const __bf16* qbase = base + (size_t)(wid * 64) * 3072;
#pragma unroll
  for (int m = 0; m < 4; ++m)
#pragma unroll
    for (int kk = 0; kk < 2; ++kk)
      aq[m][kk] =
          *(const bf16x8*)(qbase + (size_t)(m * 16 + l15) * 3072 + kk * 32 + l4 * 8);

  __syncthreads();  // K/V staged

  float m_run[4][4], l_run[4][4];
#pragma unroll
  for (int m = 0; m < 4; ++m)
#pragma unroll
    for (int r = 0; r < 4; ++r) { m_run[m][r] = -3.0e38f; l_run[m][r] = 0.f; }
  f32x4 o[4][4] = {};

  __bf16* Pw = &Pl[wid][0];

  for (int jt = 0; jt < 8; ++jt) {
    // ---- S tile [64 q][32 j] = Q K^T
    f32x4 s[4][2] = {};
#pragma unroll
    for (int kk = 0; kk < 2; ++kk) {
      bf16x8 bk[2];
#pragma unroll
      for (int n = 0; n < 2; ++n) {
        int j = jt * 32 + n * 16 + l15;
        int c8 = kk * 4 + l4;
        bk[n] = *(const bf16x8*)&Ks[(j * 8 + (c8 ^ (j & 7))) * 8];
      }
#pragma unroll
      for (int m = 0; m < 4; ++m)
#pragma unroll
        for (int n = 0; n < 2; ++n)
          s[m][n] = __builtin_amdgcn_mfma_f32_16x16x32_bf16(aq[m][kk], bk[n],
                                                            s[m][n], 0, 0, 0);
    }
    // ---- online softmax stats (row=q=(l>>4)*4+r, col=j=lane&15 group)
#pragma unroll
    for (int m = 0; m < 4; ++m)
#pragma unroll
      for (int r = 0; r < 4; ++r) {
        float a0 = s[m][0][r] * 0.125f, a1 = s[m][1][r] * 0.125f;
        float t = fmaxf(a0, a1);
        t = fmaxf(t, __shfl_xor(t, 1));
        t = fmaxf(t, __shfl_xor(t, 2));
        t = fmaxf(t, __shfl_xor(t, 4));
        t = fmaxf(t, __shfl_xor(t, 8));
        float mn = fmaxf(m_run[m][r], t);
        float al = __expf(m_run[m][r] - mn);
        m_run[m][r] = mn;
        float p0 = __expf(a0 - mn), p1 = __expf(a1 - mn);
        s[m][0][r] = p0; s[m][1][r] = p1;
        float rs = p0 + p1;
        rs += __shfl_xor(rs, 1);
        rs += __shfl_xor(rs, 2);
        rs += __shfl_xor(rs, 4);
        rs += __shfl_xor(rs, 8);
        l_run[m][r] = l_run[m][r] * al + rs;
#pragma unroll
        for (int nd = 0; nd < 4; ++nd) o[m][nd][r] *= al;
      }
    // ---- P -> LDS (bf16, swizzled), per-wave region, no barrier needed
#pragma unroll
    for (int m = 0; m < 4; ++m)
#pragma unroll
      for (int n = 0; n < 2; ++n)
#pragma unroll
        for (int r = 0; r < 4; ++r) {
          int q = m * 16 + l4 * 4 + r;
          int j = n * 16 + l15;
          Pw[q * 32 + (((j >> 3) ^ (q & 3)) * 8) + (j & 7)] = (__bf16)s[m][n][r];
        }
    // ---- read P as A-operand, V^T as B-operand, accumulate O
    bf16x8 ap[4];
#pragma unroll
    for (int m = 0; m < 4; ++m) {
      int q = m * 16 + l15;
      ap[m] = *(const bf16x8*)&Pw[q * 32 + ((l4 ^ (q & 3)) * 8)];
    }
    bf16x8 bv[4];
#pragma unroll
    for (int nd = 0; nd < 4; ++nd) {
      int d = nd * 16 + l15;
      int jb = jt * 4 + l4;
      bv[nd] = *(const bf16x8*)&Vt[d * 256 + ((jb ^ (d & 7)) * 8)];
    }
#pragma unroll
    for (int m = 0; m < 4; ++m)
#pragma unroll
      for (int nd = 0; nd < 4; ++nd)
        o[m][nd] = __builtin_amdgcn_mfma_f32_16x16x32_bf16(ap[m], bv[nd],
                                                           o[m][nd], 0, 0, 0);
  }

  // ---- normalize + store [B,L,C] layout: row=bf*256+q, col=h*64+d
  __bf16* ob = attnOut + (size_t)(bf * 256 + wid * 64) * 1024 + h * 64;
#pragma unroll
  for (int m = 0; m < 4; ++m)
#pragma unroll
    for (int r = 0; r < 4; ++r) {
      float inv = 1.0f / l_run[m][r];
#pragma unroll
      for (int nd = 0; nd < 4; ++nd)
        ob[(size_t)(m * 16 + l4 * 4 + r) * 1024 + nd * 16 + l15] =
            (__bf16)(o[m][nd][r] * inv);
    }
}

// ---------------- launch ---------------------------------------------------
extern "C" void kernel_launch(void* const* d_in, const int* in_sizes, int n_in,
                              void* d_out, int out_size, void* d_ws,
                              size_t ws_size, hipStream_t stream) {
  const float* x = (const float*)d_in[0];       // 16777216
  const float* qkv_w = (const float*)d_in[1];   // 3145728
  const float* qkv_b = (const float*)d_in[2];   // 3072
  const float* out_w = (const float*)d_in[3];   // 1048576
  const float* out_b = (const float*)d_in[4];   // 1024
  float* out = (float*)d_out;                   // 16777216 fp32

  // workspace layout (bf16), total ~168 MB
  __bf16* xb = (__bf16*)d_ws;                  // 16777216
  __bf16* qkvwb = xb + 16777216;               // 3145728
  __bf16* outwb = qkvwb + 3145728;             // 1048576
  __bf16* qkvb = outwb + 1048576;              // 16384*3072
  __bf16* attnb = qkvb + (size_t)16384 * 3072; // 16384*1024

  cvt_f32_bf16<<<8192, 256, 0, stream>>>(x, xb, 16777216 / 8);
  cvt_f32_bf16<<<1536, 256, 0, stream>>>(qkv_w, qkvwb, 3145728 / 8);
  cvt_f32_bf16<<<512, 256, 0, stream>>>(out_w, outwb, 1048576 / 8);

  // QKV: M=16384, N=3072, K=1024 -> grid 12 x 64 (768 blocks, %8==0)
  gemm256<true><<<dim3(12, 64), 512, 0, stream>>>(xb, qkvwb, qkv_b, qkvb,
                                                  16384, 3072, 1024);

  attn_kernel<<<dim3(16, 64), 256, 0, stream>>>(qkvb, attnb);

  // out-proj: M=16384, N=1024, K=1024 -> grid 4 x 64 (256 blocks, %8==0)
  gemm256<false><<<dim3(4, 64), 512, 0, stream>>>(attnb, outwb, out_b, out,
                                                  16384, 1024, 1024);
}

// Round 7
// 358.630 us; speedup vs baseline: 1.1062x; 1.1062x over previous
//
#include <hip/hip_runtime.h>

// SpatialAttention: x[4,4096,1024] fp32, F=16 -> 64 frames x 256 patches,
// H=16 heads, D=64.  Pipeline: cvt->bf16, QKV GEMM (256^2 pipelined bf16
// MFMA), per-(bf,h) attention, out-proj GEMM (fp32 out).

typedef __bf16 bf16x8 __attribute__((ext_vector_type(8)));
typedef float f32x4 __attribute__((ext_vector_type(4)));

__device__ __forceinline__ void gload_lds16(const void* g, void* l) {
  __builtin_amdgcn_global_load_lds(
      (__attribute__((address_space(1))) void*)(g),
      (__attribute__((address_space(3))) void*)(l), 16, 0, 0);
}

// ---------------- fp32 -> bf16 conversion (vectorized, 8 elems/thread) ----
__global__ __launch_bounds__(256) void cvt_f32_bf16(
    const float* __restrict__ in, __bf16* __restrict__ out, int n8) {
  int i = blockIdx.x * 256 + threadIdx.x;
  if (i >= n8) return;
  const float4* p = (const float4*)in;
  float4 a = p[2 * i];
  float4 b = p[2 * i + 1];
  bf16x8 v;
  v[0] = (__bf16)a.x; v[1] = (__bf16)a.y; v[2] = (__bf16)a.z; v[3] = (__bf16)a.w;
  v[4] = (__bf16)b.x; v[5] = (__bf16)b.y; v[6] = (__bf16)b.z; v[7] = (__bf16)b.w;
  ((bf16x8*)out)[i] = v;
}

// ---------------- GEMM 256x256, BK=64, 8 waves, pipelined (R5, proven) -----
// C[M,N] = A[M,K] * B[N,K]^T + bias.  LDS double-buffered (128 KiB), row-XOR
// swizzle (blk ^= row&7) applied on the pre-swizzled GLOBAL source (linear
// DMA dest) and on the ds_read address.  Counted vmcnt(8): staging for tile
// t+2 is issued after the tile-t read-barrier; before reading tile t+1 we
// wait vmcnt(8) (t+2's 8 loads remain in flight) + s_barrier.
template <bool BF16_OUT>
__global__ __launch_bounds__(512, 2) void gemm256(
    const __bf16* __restrict__ A, const __bf16* __restrict__ Bm,
    const float* __restrict__ bias, void* __restrict__ Cv,
    int M, int N, int K) {
  __shared__ alignas(16) __bf16 Al[2][256 * 64];  // 64 KB
  __shared__ alignas(16) __bf16 Bl[2][256 * 64];  // 64 KB

  const int tid = threadIdx.x, lane = tid & 63, wid = tid >> 6;
  const int wr = wid >> 2, wc = wid & 3;  // 2 x 4 waves
  const int l15 = lane & 15, l4 = lane >> 4;

  // XCD-aware bijective swizzle (grid sizes here are multiples of 8)
  const int nwg = gridDim.x * gridDim.y;
  const int bid = blockIdx.y * gridDim.x + blockIdx.x;
  const int q = nwg >> 3;
  const int swz = (bid & 7) * q + (bid >> 3);
  const int bn = swz % gridDim.x, bm = swz / gridDim.x;

  const int NT = K >> 6;  // K-tiles of 64

  const __bf16* gA[4];
  const __bf16* gB[4];
#pragma unroll
  for (int c = 0; c < 4; ++c) {
    int seg = c * 512 + tid;
    int row = seg >> 3, bl = (seg & 7) ^ (row & 7);
    gA[c] = A + (size_t)(bm * 256 + row) * K + bl * 8;
    gB[c] = Bm + (size_t)(bn * 256 + row) * K + bl * 8;
  }

#define STAGE(b)                                         \
  {                                                      \
    _Pragma("unroll") for (int c = 0; c < 4; ++c) {      \
      gload_lds16(gA[c], &Al[b][(c * 512 + tid) * 8]);   \
      gA[c] += 64;                                       \
    }                                                    \
    _Pragma("unroll") for (int c = 0; c < 4; ++c) {      \
      gload_lds16(gB[c], &Bl[b][(c * 512 + tid) * 8]);   \
      gB[c] += 64;                                       \
    }                                                    \
  }

  const int rsw = l15 & 7;
  const int pk0 = ((l4) ^ rsw) * 8;      // k-slice 0
  const int pk1 = ((4 + l4) ^ rsw) * 8;  // k-slice 1
  const int aRow = (wr * 128 + l15) * 64;
  const int bRow = (wc * 64 + l15) * 64;

  f32x4 acc[8][4] = {};

  STAGE(0);
  STAGE(1);
  asm volatile("s_waitcnt vmcnt(8)" ::: "memory");
  __builtin_amdgcn_s_barrier();

  for (int t = 0; t < NT; ++t) {
    const __bf16* Ab = &Al[t & 1][0];
    const __bf16* Bb = &Bl[t & 1][0];
    const bool hasStage = (t + 2 < NT);
    const bool hasNext = (t + 1 < NT);

    // ---- phase 0: kk=0, m 0..3
    bf16x8 b0 = *(const bf16x8*)(Bb + bRow + 0 * 1024 + pk0);
    bf16x8 b1 = *(const bf16x8*)(Bb + bRow + 1 * 1024 + pk0);
    bf16x8 b2 = *(const bf16x8*)(Bb + bRow + 2 * 1024 + pk0);
    bf16x8 b3 = *(const bf16x8*)(Bb + bRow + 3 * 1024 + pk0);
    bf16x8 x0 = *(const bf16x8*)(Ab + aRow + 0 * 1024 + pk0);
    bf16x8 x1 = *(const bf16x8*)(Ab + aRow + 1 * 1024 + pk0);
    bf16x8 x2 = *(const bf16x8*)(Ab + aRow + 2 * 1024 + pk0);
    bf16x8 x3 = *(const bf16x8*)(Ab + aRow + 3 * 1024 + pk0);
    __builtin_amdgcn_s_setprio(1);
#pragma unroll
    for (int n = 0; n < 4; ++n) {
      bf16x8 bb = n == 0 ? b0 : n == 1 ? b1 : n == 2 ? b2 : b3;
      acc[0][n] = __builtin_amdgcn_mfma_f32_16x16x32_bf16(x0, bb, acc[0][n], 0, 0, 0);
      acc[1][n] = __builtin_amdgcn_mfma_f32_16x16x32_bf16(x1, bb, acc[1][n], 0, 0, 0);
      acc[2][n] = __builtin_amdgcn_mfma_f32_16x16x32_bf16(x2, bb, acc[2][n], 0, 0, 0);
      acc[3][n] = __builtin_amdgcn_mfma_f32_16x16x32_bf16(x3, bb, acc[3][n], 0, 0, 0);
    }
    __builtin_amdgcn_s_setprio(0);

    // ---- phase 1: kk=0, m 4..7
    x0 = *(const bf16x8*)(Ab + aRow + 4 * 1024 + pk0);
    x1 = *(const bf16x8*)(Ab + aRow + 5 * 1024 + pk0);
    x2 = *(const bf16x8*)(Ab + aRow + 6 * 1024 + pk0);
    x3 = *(const bf16x8*)(Ab + aRow + 7 * 1024 + pk0);
    __builtin_amdgcn_s_setprio(1);
#pragma unroll
    for (int n = 0; n < 4; ++n) {
      bf16x8 bb = n == 0 ? b0 : n == 1 ? b1 : n == 2 ? b2 : b3;
      acc[4][n] = __builtin_amdgcn_mfma_f32_16x16x32_bf16(x0, bb, acc[4][n], 0, 0, 0);
      acc[5][n] = __builtin_amdgcn_mfma_f32_16x16x32_bf16(x1, bb, acc[5][n], 0, 0, 0);
      acc[6][n] = __builtin_amdgcn_mfma_f32_16x16x32_bf16(x2, bb, acc[6][n], 0, 0, 0);
      acc[7][n] = __builtin_amdgcn_mfma_f32_16x16x32_bf16(x3, bb, acc[7][n], 0, 0, 0);
    }
    __builtin_amdgcn_s_setprio(0);

    // ---- phase 2: kk=1, m 0..3
    b0 = *(const bf16x8*)(Bb + bRow + 0 * 1024 + pk1);
    b1 = *(const bf16x8*)(Bb + bRow + 1 * 1024 + pk1);
    b2 = *(const bf16x8*)(Bb + bRow + 2 * 1024 + pk1);
    b3 = *(const bf16x8*)(Bb + bRow + 3 * 1024 + pk1);
    x0 = *(const bf16x8*)(Ab + aRow + 0 * 1024 + pk1);
    x1 = *(const bf16x8*)(Ab + aRow + 1 * 1024 + pk1);
    x2 = *(const bf16x8*)(Ab + aRow + 2 * 1024 + pk1);
    x3 = *(const bf16x8*)(Ab + aRow + 3 * 1024 + pk1);
    __builtin_amdgcn_s_setprio(1);
#pragma unroll
    for (int n = 0; n < 4; ++n) {
      bf16x8 bb = n == 0 ? b0 : n == 1 ? b1 : n == 2 ? b2 : b3;
      acc[0][n] = __builtin_amdgcn_mfma_f32_16x16x32_bf16(x0, bb, acc[0][n], 0, 0, 0);
      acc[1][n] = __builtin_amdgcn_mfma_f32_16x16x32_bf16(x1, bb, acc[1][n], 0, 0, 0);
      acc[2][n] = __builtin_amdgcn_mfma_f32_16x16x32_bf16(x2, bb, acc[2][n], 0, 0, 0);
      acc[3][n] = __builtin_amdgcn_mfma_f32_16x16x32_bf16(x3, bb, acc[3][n], 0, 0, 0);
    }
    __builtin_amdgcn_s_setprio(0);

    // ---- phase 3: kk=1, m 4..7 + staging + pipelined sync
    x0 = *(const bf16x8*)(Ab + aRow + 4 * 1024 + pk1);
    x1 = *(const bf16x8*)(Ab + aRow + 5 * 1024 + pk1);
    x2 = *(const bf16x8*)(Ab + aRow + 6 * 1024 + pk1);
    x3 = *(const bf16x8*)(Ab + aRow + 7 * 1024 + pk1);
    asm volatile("s_waitcnt lgkmcnt(0)" ::: "memory");
    __builtin_amdgcn_sched_barrier(0);
    __builtin_amdgcn_s_barrier();  // all waves done reading buf[t&1]
    if (hasStage) STAGE(t & 1);    // tile t+2 -> buf[t&1] (DMA, async)
    __builtin_amdgcn_s_setprio(1);
#pragma unroll
    for (int n = 0; n < 4; ++n) {
      bf16x8 bb = n == 0 ? b0 : n == 1 ? b1 : n == 2 ? b2 : b3;
      acc[4][n] = __builtin_amdgcn_mfma_f32_16x16x32_bf16(x0, bb, acc[4][n], 0, 0, 0);
      acc[5][n] = __builtin_amdgcn_mfma_f32_16x16x32_bf16(x1, bb, acc[5][n], 0, 0, 0);
      acc[6][n] = __builtin_amdgcn_mfma_f32_16x16x32_bf16(x2, bb, acc[6][n], 0, 0, 0);
      acc[7][n] = __builtin_amdgcn_mfma_f32_16x16x32_bf16(x3, bb, acc[7][n], 0, 0, 0);
    }
    __builtin_amdgcn_s_setprio(0);
    if (hasNext) {
      if (hasStage)
        asm volatile("s_waitcnt vmcnt(8)" ::: "memory");
      else
        asm volatile("s_waitcnt vmcnt(0)" ::: "memory");
      __builtin_amdgcn_s_barrier();
    }
  }
#undef STAGE

  // ---- epilogue: D col=lane&15, row=(lane>>4)*4+r
  const int r0 = l4 * 4;
#pragma unroll
  for (int m = 0; m < 8; ++m) {
#pragma unroll
    for (int n = 0; n < 4; ++n) {
      int row = bm * 256 + wr * 128 + m * 16 + r0;
      int col = bn * 256 + wc * 64 + n * 16 + l15;
      float bb = bias[col];
#pragma unroll
      for (int r = 0; r < 4; ++r) {
        float v = acc[m][n][r] + bb;
        if (BF16_OUT)
          ((__bf16*)Cv)[(size_t)(row + r) * N + col] = (__bf16)v;
        else
          ((float*)Cv)[(size_t)(row + r) * N + col] = v;
      }
    }
  }
}

// ---------------- attention: one block per (bf, h) ------------------------
// qkv[16384][3072] bf16.  4 waves x 64 q-rows; K,V (256x64) in LDS (K
// xor-swizzled, V transposed); online softmax over 4 j-tiles of 64 with
// defer-max (THR=8) and lane-local deferred row-sum; PV in 2 half-steps.
__global__ __launch_bounds__(256, 2) void attn_kernel(
    const __bf16* __restrict__ qkv, __bf16* __restrict__ attnOut) {
  __shared__ alignas(16) __bf16 Ks[256 * 64];       // 32 KB, swizzled
  __shared__ alignas(16) __bf16 Vt[64 * 256];       // 32 KB, transposed+swz
  __shared__ alignas(16) __bf16 Pl[4][64 * 32];     // 16 KB, per-wave P tile

  const int h = blockIdx.x, bf = blockIdx.y;
  const int tid = threadIdx.x, lane = tid & 63, wid = tid >> 6;
  const int l15 = lane & 15, l4 = lane >> 4;

  const __bf16* base = qkv + (size_t)(bf * 256) * 3072 + h * 64;

  // --- stage K: pre-swizzled global source -> linear LDS write (rule 21)
#pragma unroll
  for (int rr = 0; rr < 8; ++rr) {
    int s = rr * 256 + wid * 64 + lane;
    int r = s >> 3, t = s & 7, c8 = t ^ (r & 7);
    gload_lds16(base + 1024 + (size_t)r * 3072 + c8 * 8, &Ks[s * 8]);
  }

  // --- stage V transposed: thread t owns global row j=t (64 elems)
  {
    const __bf16* vrow = base + 2048 + (size_t)tid * 3072;
    bf16x8 vv[8];
#pragma unroll
    for (int b8 = 0; b8 < 8; ++b8) vv[b8] = *(const bf16x8*)(vrow + b8 * 8);
#pragma unroll
    for (int b8 = 0; b8 < 8; ++b8)
#pragma unroll
      for (int e = 0; e < 8; ++e) {
        int d = b8 * 8 + e;
        Vt[d * 256 + (((tid >> 3) ^ (d & 7)) * 8) + (tid & 7)] = vv[b8][e];
      }
  }

  // --- Q fragments (A-operand: row=lane&15, k=(lane>>4)*8+j), direct global
  bf16x8 aq[4][2];
  const __bf16* qbase = base + (size_t)(wid * 64) * 3072;
#pragma unroll
  for (int m = 0; m < 4; ++m)
#pragma unroll
    for (int kk = 0; kk < 2; ++kk)
      aq[m][kk] =
          *(const bf16x8*)(qbase + (size_t)(m * 16 + l15) * 3072 + kk * 32 + l4 * 8);

  __syncthreads();  // K/V staged

  float m_run[4][4], lsum[4][4];
#pragma unroll
  for (int m = 0; m < 4; ++m)
#pragma unroll
    for (int r = 0; r < 4; ++r) { m_run[m][r] = -3.0e38f; lsum[m][r] = 0.f; }
  f32x4 o[4][4] = {};

  __bf16* Pw = &Pl[wid][0];

  for (int jt = 0; jt < 4; ++jt) {
    // ---- S tile [64 q][64 j] = Q K^T
    f32x4 s[4][4] = {};
#pragma unroll
    for (int kk = 0; kk < 2; ++kk) {
      bf16x8 bk[4];
#pragma unroll
      for (int n = 0; n < 4; ++n) {
        int j = jt * 64 + n * 16 + l15;
        int c8 = kk * 4 + l4;
        bk[n] = *(const bf16x8*)&Ks[(j * 8 + (c8 ^ (j & 7))) * 8];
      }
      __builtin_amdgcn_s_setprio(1);
#pragma unroll
      for (int m = 0; m < 4; ++m)
#pragma unroll
        for (int n = 0; n < 4; ++n)
          s[m][n] = __builtin_amdgcn_mfma_f32_16x16x32_bf16(aq[m][kk], bk[n],
                                                            s[m][n], 0, 0, 0);
      __builtin_amdgcn_s_setprio(0);
    }
    // ---- scale, group-max (4 shfl per row), defer-max check
#pragma unroll
    for (int m = 0; m < 4; ++m)
#pragma unroll
      for (int n = 0; n < 4; ++n) s[m][n] *= 0.125f;
    float tloc[4][4];
    float grow = 0.f;
#pragma unroll
    for (int m = 0; m < 4; ++m)
#pragma unroll
      for (int r = 0; r < 4; ++r) {
        float t = fmaxf(fmaxf(s[m][0][r], s[m][1][r]),
                        fmaxf(s[m][2][r], s[m][3][r]));
        t = fmaxf(t, __shfl_xor(t, 1));
        t = fmaxf(t, __shfl_xor(t, 2));
        t = fmaxf(t, __shfl_xor(t, 4));
        t = fmaxf(t, __shfl_xor(t, 8));
        tloc[m][r] = t;
        grow = fmaxf(grow, t - m_run[m][r]);
      }
    if (__any(grow > 8.0f)) {
#pragma unroll
      for (int m = 0; m < 4; ++m)
#pragma unroll
        for (int r = 0; r < 4; ++r) {
          float mn = fmaxf(m_run[m][r], tloc[m][r]);
          float al = __expf(m_run[m][r] - mn);
          m_run[m][r] = mn;
          lsum[m][r] *= al;
#pragma unroll
          for (int nd = 0; nd < 4; ++nd) o[m][nd][r] *= al;
        }
    }
    // ---- exponentiate (lane-local partial row-sum, no shuffles)
#pragma unroll
    for (int m = 0; m < 4; ++m)
#pragma unroll
      for (int r = 0; r < 4; ++r) {
        float p0 = __expf(s[m][0][r] - m_run[m][r]);
        float p1 = __expf(s[m][1][r] - m_run[m][r]);
        float p2 = __expf(s[m][2][r] - m_run[m][r]);
        float p3 = __expf(s[m][3][r] - m_run[m][r]);
        s[m][0][r] = p0; s[m][1][r] = p1; s[m][2][r] = p2; s[m][3][r] = p3;
        lsum[m][r] += (p0 + p1) + (p2 + p3);
      }
    // ---- PV in two 32-wide half-steps through the per-wave P tile
#pragma unroll
    for (int hh = 0; hh < 2; ++hh) {
#pragma unroll
      for (int m = 0; m < 4; ++m)
#pragma unroll
        for (int nn = 0; nn < 2; ++nn)
#pragma unroll
          for (int r = 0; r < 4; ++r) {
            int qr = m * 16 + l4 * 4 + r;
            int j = nn * 16 + l15;
            Pw[qr * 32 + (((j >> 3) ^ (qr & 3)) * 8) + (j & 7)] =
                (__bf16)s[m][2 * hh + nn][r];
          }
      bf16x8 ap[4];
#pragma unroll
      for (int m = 0; m < 4; ++m) {
        int qr = m * 16 + l15;
        ap[m] = *(const bf16x8*)&Pw[qr * 32 + ((l4 ^ (qr & 3)) * 8)];
      }
      bf16x8 bv[4];
#pragma unroll
      for (int nd = 0; nd < 4; ++nd) {
        int d = nd * 16 + l15;
        int jb = jt * 8 + hh * 4 + l4;
        bv[nd] = *(const bf16x8*)&Vt[d * 256 + ((jb ^ (d & 7)) * 8)];
      }
      __builtin_amdgcn_s_setprio(1);
#pragma unroll
      for (int m = 0; m < 4; ++m)
#pragma unroll
        for (int nd = 0; nd < 4; ++nd)
          o[m][nd] = __builtin_amdgcn_mfma_f32_16x16x32_bf16(ap[m], bv[nd],
                                                             o[m][nd], 0, 0, 0);
      __builtin_amdgcn_s_setprio(0);
    }
  }

  // ---- final row-sum reduce (once) + normalize + store [B,L,C]
  __bf16* ob = attnOut + (size_t)(bf * 256 + wid * 64) * 1024 + h * 64;
#pragma unroll
  for (int m = 0; m < 4; ++m)
#pragma unroll
    for (int r = 0; r < 4; ++r) {
      float rs = lsum[m][r];
      rs += __shfl_xor(rs, 1);
      rs += __shfl_xor(rs, 2);
      rs += __shfl_xor(rs, 4);
      rs += __shfl_xor(rs, 8);
      float inv = 1.0f / rs;
#pragma unroll
      for (int nd = 0; nd < 4; ++nd)
        ob[(size_t)(m * 16 + l4 * 4 + r) * 1024 + nd * 16 + l15] =
            (__bf16)(o[m][nd][r] * inv);
    }
}

// ---------------- launch ---------------------------------------------------
extern "C" void kernel_launch(void* const* d_in, const int* in_sizes, int n_in,
                              void* d_out, int out_size, void* d_ws,
                              size_t ws_size, hipStream_t stream) {
  const float* x = (const float*)d_in[0];       // 16777216
  const float* qkv_w = (const float*)d_in[1];   // 3145728
  const float* qkv_b = (const float*)d_in[2];   // 3072
  const float* out_w = (const float*)d_in[3];   // 1048576
  const float* out_b = (const float*)d_in[4];   // 1024
  float* out = (float*)d_out;                   // 16777216 fp32

  // workspace layout (bf16), total ~168 MB
  __bf16* xb = (__bf16*)d_ws;                  // 16777216
  __bf16* qkvwb = xb + 16777216;               // 3145728
  __bf16* outwb = qkvwb + 3145728;             // 1048576
  __bf16* qkvb = outwb + 1048576;              // 16384*3072
  __bf16* attnb = qkvb + (size_t)16384 * 3072; // 16384*1024

  cvt_f32_bf16<<<8192, 256, 0, stream>>>(x, xb, 16777216 / 8);
  cvt_f32_bf16<<<1536, 256, 0, stream>>>(qkv_w, qkvwb, 3145728 / 8);
  cvt_f32_bf16<<<512, 256, 0, stream>>>(out_w, outwb, 1048576 / 8);

  // QKV: M=16384, N=3072, K=1024 -> grid 12 x 64 (768 blocks, %8==0)
  gemm256<true><<<dim3(12, 64), 512, 0, stream>>>(xb, qkvwb, qkv_b, qkvb,
                                                  16384, 3072, 1024);

  attn_kernel<<<dim3(16, 64), 256, 0, stream>>>(qkvb, attnb);

  // out-proj: M=16384, N=1024, K=1024 -> grid 4 x 64 (256 blocks, %8==0)
  gemm256<false><<<dim3(4, 64), 512, 0, stream>>>(attnb, outwb, out_b, out,
                                                  16384, 1024, 1024);
}

// Round 8
// 339.452 us; speedup vs baseline: 1.1687x; 1.0565x over previous
//
#include <hip/hip_runtime.h>

// SpatialAttention: x[4,4096,1024] fp32, F=16 -> 64 frames x 256 patches,
// H=16 heads, D=64.  Pipeline: cvt->bf16, QKV GEMM (256^2 pipelined bf16
// MFMA, writes per-head panels), per-(bf,h) attention, out-proj GEMM.

typedef __bf16 bf16x8 __attribute__((ext_vector_type(8)));
typedef float f32x4 __attribute__((ext_vector_type(4)));

__device__ __forceinline__ void gload_lds16(const void* g, void* l) {
  __builtin_amdgcn_global_load_lds(
      (__attribute__((address_space(1))) void*)(g),
      (__attribute__((address_space(3))) void*)(l), 16, 0, 0);
}

// ---------------- fp32 -> bf16 conversion (vectorized, 8 elems/thread) ----
__global__ __launch_bounds__(256) void cvt_f32_bf16(
    const float* __restrict__ in, __bf16* __restrict__ out, int n8) {
  int i = blockIdx.x * 256 + threadIdx.x;
  if (i >= n8) return;
  const float4* p = (const float4*)in;
  float4 a = p[2 * i];
  float4 b = p[2 * i + 1];
  bf16x8 v;
  v[0] = (__bf16)a.x; v[1] = (__bf16)a.y; v[2] = (__bf16)a.z; v[3] = (__bf16)a.w;
  v[4] = (__bf16)b.x; v[5] = (__bf16)b.y; v[6] = (__bf16)b.z; v[7] = (__bf16)b.w;
  ((bf16x8*)out)[i] = v;
}

// ---------------- GEMM 256x256, BK=64, 8 waves, pipelined (R5, proven) -----
// C = A[M,K]*B[N,K]^T + bias.  MODE 0: fp32 row-major C[M,N].
// MODE 1: bf16 QKV head-panels qkv3[sel][bf*16+h][p][d] = [3][1024][256][64].
template <int MODE>
__global__ __launch_bounds__(512, 2) void gemm256(
    const __bf16* __restrict__ A, const __bf16* __restrict__ Bm,
    const float* __restrict__ bias, void* __restrict__ Cv,
    int M, int N, int K) {
  __shared__ alignas(16) __bf16 Al[2][256 * 64];  // 64 KB
  __shared__ alignas(16) __bf16 Bl[2][256 * 64];  // 64 KB

  const int tid = threadIdx.x, lane = tid & 63, wid = tid >> 6;
  const int wr = wid >> 2, wc = wid & 3;  // 2 x 4 waves
  const int l15 = lane & 15, l4 = lane >> 4;

  // XCD-aware bijective swizzle (grid sizes here are multiples of 8)
  const int nwg = gridDim.x * gridDim.y;
  const int bid = blockIdx.y * gridDim.x + blockIdx.x;
  const int q = nwg >> 3;
  const int swz = (bid & 7) * q + (bid >> 3);
  const int bn = swz % gridDim.x, bm = swz / gridDim.x;

  const int NT = K >> 6;  // K-tiles of 64

  const __bf16* gA[4];
  const __bf16* gB[4];
#pragma unroll
  for (int c = 0; c < 4; ++c) {
    int seg = c * 512 + tid;
    int row = seg >> 3, bl = (seg & 7) ^ (row & 7);
    gA[c] = A + (size_t)(bm * 256 + row) * K + bl * 8;
    gB[c] = Bm + (size_t)(bn * 256 + row) * K + bl * 8;
  }

#define STAGE(b)                                         \
  {                                                      \
    _Pragma("unroll") for (int c = 0; c < 4; ++c) {      \
      gload_lds16(gA[c], &Al[b][(c * 512 + tid) * 8]);   \
      gA[c] += 64;                                       \
    }                                                    \
    _Pragma("unroll") for (int c = 0; c < 4; ++c) {      \
      gload_lds16(gB[c], &Bl[b][(c * 512 + tid) * 8]);   \
      gB[c] += 64;                                       \
    }                                                    \
  }

  const int rsw = l15 & 7;
  const int pk0 = ((l4) ^ rsw) * 8;      // k-slice 0
  const int pk1 = ((4 + l4) ^ rsw) * 8;  // k-slice 1
  const int aRow = (wr * 128 + l15) * 64;
  const int bRow = (wc * 64 + l15) * 64;

  f32x4 acc[8][4] = {};

  STAGE(0);
  STAGE(1);
  asm volatile("s_waitcnt vmcnt(8)" ::: "memory");
  __builtin_amdgcn_s_barrier();

  for (int t = 0; t < NT; ++t) {
    const __bf16* Ab = &Al[t & 1][0];
    const __bf16* Bb = &Bl[t & 1][0];
    const bool hasStage = (t + 2 < NT);
    const bool hasNext = (t + 1 < NT);

    // ---- phase 0: kk=0, m 0..3
    bf16x8 b0 = *(const bf16x8*)(Bb + bRow + 0 * 1024 + pk0);
    bf16x8 b1 = *(const bf16x8*)(Bb + bRow + 1 * 1024 + pk0);
    bf16x8 b2 = *(const bf16x8*)(Bb + bRow + 2 * 1024 + pk0);
    bf16x8 b3 = *(const bf16x8*)(Bb + bRow + 3 * 1024 + pk0);
    bf16x8 x0 = *(const bf16x8*)(Ab + aRow + 0 * 1024 + pk0);
    bf16x8 x1 = *(const bf16x8*)(Ab + aRow + 1 * 1024 + pk0);
    bf16x8 x2 = *(const bf16x8*)(Ab + aRow + 2 * 1024 + pk0);
    bf16x8 x3 = *(const bf16x8*)(Ab + aRow + 3 * 1024 + pk0);
    __builtin_amdgcn_s_setprio(1);
#pragma unroll
    for (int n = 0; n < 4; ++n) {
      bf16x8 bb = n == 0 ? b0 : n == 1 ? b1 : n == 2 ? b2 : b3;
      acc[0][n] = __builtin_amdgcn_mfma_f32_16x16x32_bf16(x0, bb, acc[0][n], 0, 0, 0);
      acc[1][n] = __builtin_amdgcn_mfma_f32_16x16x32_bf16(x1, bb, acc[1][n], 0, 0, 0);
      acc[2][n] = __builtin_amdgcn_mfma_f32_16x16x32_bf16(x2, bb, acc[2][n], 0, 0, 0);
      acc[3][n] = __builtin_amdgcn_mfma_f32_16x16x32_bf16(x3, bb, acc[3][n], 0, 0, 0);
    }
    __builtin_amdgcn_s_setprio(0);

    // ---- phase 1: kk=0, m 4..7
    x0 = *(const bf16x8*)(Ab + aRow + 4 * 1024 + pk0);
    x1 = *(const bf16x8*)(Ab + aRow + 5 * 1024 + pk0);
    x2 = *(const bf16x8*)(Ab + aRow + 6 * 1024 + pk0);
    x3 = *(const bf16x8*)(Ab + aRow + 7 * 1024 + pk0);
    __builtin_amdgcn_s_setprio(1);
#pragma unroll
    for (int n = 0; n < 4; ++n) {
      bf16x8 bb = n == 0 ? b0 : n == 1 ? b1 : n == 2 ? b2 : b3;
      acc[4][n] = __builtin_amdgcn_mfma_f32_16x16x32_bf16(x0, bb, acc[4][n], 0, 0, 0);
      acc[5][n] = __builtin_amdgcn_mfma_f32_16x16x32_bf16(x1, bb, acc[5][n], 0, 0, 0);
      acc[6][n] = __builtin_amdgcn_mfma_f32_16x16x32_bf16(x2, bb, acc[6][n], 0, 0, 0);
      acc[7][n] = __builtin_amdgcn_mfma_f32_16x16x32_bf16(x3, bb, acc[7][n], 0, 0, 0);
    }
    __builtin_amdgcn_s_setprio(0);

    // ---- phase 2: kk=1, m 0..3
    b0 = *(const bf16x8*)(Bb + bRow + 0 * 1024 + pk1);
    b1 = *(const bf16x8*)(Bb + bRow + 1 * 1024 + pk1);
    b2 = *(const bf16x8*)(Bb + bRow + 2 * 1024 + pk1);
    b3 = *(const bf16x8*)(Bb + bRow + 3 * 1024 + pk1);
    x0 = *(const bf16x8*)(Ab + aRow + 0 * 1024 + pk1);
    x1 = *(const bf16x8*)(Ab + aRow + 1 * 1024 + pk1);
    x2 = *(const bf16x8*)(Ab + aRow + 2 * 1024 + pk1);
    x3 = *(const bf16x8*)(Ab + aRow + 3 * 1024 + pk1);
    __builtin_amdgcn_s_setprio(1);
#pragma unroll
    for (int n = 0; n < 4; ++n) {
      bf16x8 bb = n == 0 ? b0 : n == 1 ? b1 : n == 2 ? b2 : b3;
      acc[0][n] = __builtin_amdgcn_mfma_f32_16x16x32_bf16(x0, bb, acc[0][n], 0, 0, 0);
      acc[1][n] = __builtin_amdgcn_mfma_f32_16x16x32_bf16(x1, bb, acc[1][n], 0, 0, 0);
      acc[2][n] = __builtin_amdgcn_mfma_f32_16x16x32_bf16(x2, bb, acc[2][n], 0, 0, 0);
      acc[3][n] = __builtin_amdgcn_mfma_f32_16x16x32_bf16(x3, bb, acc[3][n], 0, 0, 0);
    }
    __builtin_amdgcn_s_setprio(0);

    // ---- phase 3: kk=1, m 4..7 + staging + pipelined sync
    x0 = *(const bf16x8*)(Ab + aRow + 4 * 1024 + pk1);
    x1 = *(const bf16x8*)(Ab + aRow + 5 * 1024 + pk1);
    x2 = *(const bf16x8*)(Ab + aRow + 6 * 1024 + pk1);
    x3 = *(const bf16x8*)(Ab + aRow + 7 * 1024 + pk1);
    asm volatile("s_waitcnt lgkmcnt(0)" ::: "memory");
    __builtin_amdgcn_sched_barrier(0);
    __builtin_amdgcn_s_barrier();  // all waves done reading buf[t&1]
    if (hasStage) STAGE(t & 1);    // tile t+2 -> buf[t&1] (DMA, async)
    __builtin_amdgcn_s_setprio(1);
#pragma unroll
    for (int n = 0; n < 4; ++n) {
      bf16x8 bb = n == 0 ? b0 : n == 1 ? b1 : n == 2 ? b2 : b3;
      acc[4][n] = __builtin_amdgcn_mfma_f32_16x16x32_bf16(x0, bb, acc[4][n], 0, 0, 0);
      acc[5][n] = __builtin_amdgcn_mfma_f32_16x16x32_bf16(x1, bb, acc[5][n], 0, 0, 0);
      acc[6][n] = __builtin_amdgcn_mfma_f32_16x16x32_bf16(x2, bb, acc[6][n], 0, 0, 0);
      acc[7][n] = __builtin_amdgcn_mfma_f32_16x16x32_bf16(x3, bb, acc[7][n], 0, 0, 0);
    }
    __builtin_amdgcn_s_setprio(0);
    if (hasNext) {
      if (hasStage)
        asm volatile("s_waitcnt vmcnt(8)" ::: "memory");
      else
        asm volatile("s_waitcnt vmcnt(0)" ::: "memory");
      __builtin_amdgcn_s_barrier();
    }
  }
#undef STAGE

  // ---- epilogue
  const int r0 = l4 * 4;
  if (MODE == 1) {
    // head-panel store: sel = col>>10, h = (col>>6)&15, d = col&63,
    // bf = row>>8 (= bm), p = row&255.
    const int sel = bn >> 2;
    const int hh = (bn * 4 + wc) & 15;
    __bf16* pan = (__bf16*)Cv + (size_t)sel * 16777216 +
                  (size_t)(bm * 16 + hh) * 16384;
#pragma unroll
    for (int m = 0; m < 8; ++m) {
#pragma unroll
      for (int n = 0; n < 4; ++n) {
        int p = wr * 128 + m * 16 + r0;
        int d = n * 16 + l15;
        float bb = bias[bn * 256 + wc * 64 + n * 16 + l15];
#pragma unroll
        for (int r = 0; r < 4; ++r)
          pan[(size_t)(p + r) * 64 + d] = (__bf16)(acc[m][n][r] + bb);
      }
    }
  } else {
#pragma unroll
    for (int m = 0; m < 8; ++m) {
#pragma unroll
      for (int n = 0; n < 4; ++n) {
        int row = bm * 256 + wr * 128 + m * 16 + r0;
        int col = bn * 256 + wc * 64 + n * 16 + l15;
        float bb = bias[col];
#pragma unroll
        for (int r = 0; r < 4; ++r)
          ((float*)Cv)[(size_t)(row + r) * N + col] = acc[m][n][r] + bb;
      }
    }
  }
}

// ---------------- attention: one block per (bf, h) ------------------------
// qkv3 panels [3][1024][256][64] bf16 (contiguous per head).  4 waves x 64
// q-rows; K,V in LDS (K xor-swizzled via coalesced DMA, V transposed);
// online softmax over 4 j-tiles of 64 with defer-max + lane-local row-sum;
// vectorized output store through per-wave LDS transpose.
__global__ __launch_bounds__(256, 2) void attn_kernel(
    const __bf16* __restrict__ qkv3, __bf16* __restrict__ attnOut) {
  __shared__ alignas(16) __bf16 Ks[256 * 64];       // 32 KB, swizzled
  __shared__ alignas(16) __bf16 Vt[64 * 256];       // 32 KB, transposed+swz
  __shared__ alignas(16) __bf16 Pl[4][64 * 32];     // 16 KB, per-wave P tile

  const int h = blockIdx.x, bf = blockIdx.y;
  const int tid = threadIdx.x, lane = tid & 63, wid = tid >> 6;
  const int l15 = lane & 15, l4 = lane >> 4;

  const size_t g = (size_t)(bf * 16 + h) * 16384;
  const __bf16* Qp = qkv3 + g;
  const __bf16* Kp = qkv3 + 16777216 + g;
  const __bf16* Vp = qkv3 + 33554432 + g;

  // --- stage K: contiguous panel, pre-swizzled source granules.
  // Ks granule s=(r,t) holds K[r][(t^(r&7))*8..]; each 8-lane group reads one
  // permuted 128 B row -> fully coalesced DMA.
#pragma unroll
  for (int rr = 0; rr < 8; ++rr) {
    int s = rr * 256 + tid;
    int r = s >> 3, t = s & 7, c8 = t ^ (r & 7);
    gload_lds16(Kp + r * 64 + c8 * 8, &Ks[s * 8]);
  }

  // --- stage V transposed: thread t owns panel row j=t (64 elems, 128 B)
  {
    const __bf16* vrow = Vp + (size_t)tid * 64;
    bf16x8 vv[8];
#pragma unroll
    for (int b8 = 0; b8 < 8; ++b8) vv[b8] = *(const bf16x8*)(vrow + b8 * 8);
#pragma unroll
    for (int b8 = 0; b8 < 8; ++b8)
#pragma unroll
      for (int e = 0; e < 8; ++e) {
        int d = b8 * 8 + e;
        Vt[d * 256 + (((tid >> 3) ^ (d & 7)) * 8) + (tid & 7)] = vv[b8][e];
      }
  }

  // --- Q fragments (A-operand: row=lane&15, k=(lane>>4)*8+j), from panel
  bf16x8 aq[4][2];
#pragma unroll
  for (int m = 0; m < 4; ++m)
#pragma unroll
    for (int kk = 0; kk < 2; ++kk)
      aq[m][kk] = *(const bf16x8*)(Qp + (size_t)(wid * 64 + m * 16 + l15) * 64 +
                                   kk * 32 + l4 * 8);

  __syncthreads();  // K/V staged

  float m_run[4][4], lsum[4][4];
#pragma unroll
  for (int m = 0; m < 4; ++m)
#pragma unroll
    for (int r = 0; r < 4; ++r) { m_run[m][r] = -3.0e38f; lsum[m][r] = 0.f; }
  f32x4 o[4][4] = {};

  __bf16* Pw = &Pl[wid][0];

  for (int jt = 0; jt < 4; ++jt) {
    // ---- S tile [64 q][64 j] = Q K^T
    f32x4 s[4][4] = {};
#pragma unroll
    for (int kk = 0; kk < 2; ++kk) {
      bf16x8 bk[4];
#pragma unroll
      for (int n = 0; n < 4; ++n) {
        int j = jt * 64 + n * 16 + l15;
        int c8 = kk * 4 + l4;
        bk[n] = *(const bf16x8*)&Ks[(j * 8 + (c8 ^ (j & 7))) * 8];
      }
      __builtin_amdgcn_s_setprio(1);
#pragma unroll
      for (int m = 0; m < 4; ++m)
#pragma unroll
        for (int n = 0; n < 4; ++n)
          s[m][n] = __builtin_amdgcn_mfma_f32_16x16x32_bf16(aq[m][kk], bk[n],
                                                            s[m][n], 0, 0, 0);
      __builtin_amdgcn_s_setprio(0);
    }
    // ---- scale, group-max (4 shfl per row), defer-max check
#pragma unroll
    for (int m = 0; m < 4; ++m)
#pragma unroll
      for (int n = 0; n < 4; ++n) s[m][n] *= 0.125f;
    float tloc[4][4];
    float grow = 0.f;
#pragma unroll
    for (int m = 0; m < 4; ++m)
#pragma unroll
      for (int r = 0; r < 4; ++r) {
        float t = fmaxf(fmaxf(s[m][0][r], s[m][1][r]),
                        fmaxf(s[m][2][r], s[m][3][r]));
        t = fmaxf(t, __shfl_xor(t, 1));
        t = fmaxf(t, __shfl_xor(t, 2));
        t = fmaxf(t, __shfl_xor(t, 4));
        t = fmaxf(t, __shfl_xor(t, 8));
        tloc[m][r] = t;
        grow = fmaxf(grow, t - m_run[m][r]);
      }
    if (__any(grow > 8.0f)) {
#pragma unroll
      for (int m = 0; m < 4; ++m)
#pragma unroll
        for (int r = 0; r < 4; ++r) {
          float mn = fmaxf(m_run[m][r], tloc[m][r]);
          float al = __expf(m_run[m][r] - mn);
          m_run[m][r] = mn;
          lsum[m][r] *= al;
#pragma unroll
          for (int nd = 0; nd < 4; ++nd) o[m][nd][r] *= al;
        }
    }
    // ---- exponentiate (lane-local partial row-sum, no shuffles)
#pragma unroll
    for (int m = 0; m < 4; ++m)
#pragma unroll
      for (int r = 0; r < 4; ++r) {
        float p0 = __expf(s[m][0][r] - m_run[m][r]);
        float p1 = __expf(s[m][1][r] - m_run[m][r]);
        float p2 = __expf(s[m][2][r] - m_run[m][r]);
        float p3 = __expf(s[m][3][r] - m_run[m][r]);
        s[m][0][r] = p0; s[m][1][r] = p1; s[m][2][r] = p2; s[m][3][r] = p3;
        lsum[m][r] += (p0 + p1) + (p2 + p3);
      }
    // ---- PV in two 32-wide half-steps through the per-wave P tile
#pragma unroll
    for (int hh = 0; hh < 2; ++hh) {
#pragma unroll
      for (int m = 0; m < 4; ++m)
#pragma unroll
        for (int nn = 0; nn < 2; ++nn)
#pragma unroll
          for (int r = 0; r < 4; ++r) {
            int qr = m * 16 + l4 * 4 + r;
            int j = nn * 16 + l15;
            Pw[qr * 32 + (((j >> 3) ^ (qr & 3)) * 8) + (j & 7)] =
                (__bf16)s[m][2 * hh + nn][r];
          }
      bf16x8 ap[4];
#pragma unroll
      for (int m = 0; m < 4; ++m) {
        int qr = m * 16 + l15;
        ap[m] = *(const bf16x8*)&Pw[qr * 32 + ((l4 ^ (qr & 3)) * 8)];
      }
      bf16x8 bv[4];
#pragma unroll
      for (int nd = 0; nd < 4; ++nd) {
        int d = nd * 16 + l15;
        int jb = jt * 8 + hh * 4 + l4;
        bv[nd] = *(const bf16x8*)&Vt[d * 256 + ((jb ^ (d & 7)) * 8)];
      }
      __builtin_amdgcn_s_setprio(1);
#pragma unroll
      for (int m = 0; m < 4; ++m)
#pragma unroll
        for (int nd = 0; nd < 4; ++nd)
          o[m][nd] = __builtin_amdgcn_mfma_f32_16x16x32_bf16(ap[m], bv[nd],
                                                             o[m][nd], 0, 0, 0);
      __builtin_amdgcn_s_setprio(0);
    }
  }

  // ---- final row-sum reduce + normalize
  float inv[4][4];
#pragma unroll
  for (int m = 0; m < 4; ++m)
#pragma unroll
    for (int r = 0; r < 4; ++r) {
      float rs = lsum[m][r];
      rs += __shfl_xor(rs, 1);
      rs += __shfl_xor(rs, 2);
      rs += __shfl_xor(rs, 4);
      rs += __shfl_xor(rs, 8);
      inv[m][r] = 1.0f / rs;
    }

  // ---- vectorized store via per-wave LDS transpose (Pw free now).
  // chunk c covers cols c*32..c*32+31; then 16B/lane dwordx4 stores.
  __bf16* ob = attnOut + (size_t)(bf * 256 + wid * 64) * 1024 + h * 64;
#pragma unroll
  for (int c = 0; c < 2; ++c) {
#pragma unroll
    for (int m = 0; m < 4; ++m)
#pragma unroll
      for (int nn = 0; nn < 2; ++nn) {
        int nd = c * 2 + nn;
#pragma unroll
        for (int r = 0; r < 4; ++r)
          Pw[(m * 16 + l4 * 4 + r) * 32 + nn * 16 + l15] =
              (__bf16)(o[m][nd][r] * inv[m][r]);
      }
#pragma unroll
    for (int i = 0; i < 4; ++i) {
      int rr = i * 16 + (lane >> 2);
      bf16x8 v = *(const bf16x8*)&Pw[rr * 32 + (lane & 3) * 8];
      *(bf16x8*)(ob + (size_t)rr * 1024 + c * 32 + (lane & 3) * 8) = v;
    }
  }
}

// ---------------- launch ---------------------------------------------------
extern "C" void kernel_launch(void* const* d_in, const int* in_sizes, int n_in,
                              void* d_out, int out_size, void* d_ws,
                              size_t ws_size, hipStream_t stream) {
  const float* x = (const float*)d_in[0];       // 16777216
  const float* qkv_w = (const float*)d_in[1];   // 3145728
  const float* qkv_b = (const float*)d_in[2];   // 3072
  const float* out_w = (const float*)d_in[3];   // 1048576
  const float* out_b = (const float*)d_in[4];   // 1024
  float* out = (float*)d_out;                   // 16777216 fp32

  // workspace layout (bf16), total ~168 MB
  __bf16* xb = (__bf16*)d_ws;                  // 16777216
  __bf16* qkvwb = xb + 16777216;               // 3145728
  __bf16* outwb = qkvwb + 3145728;             // 1048576
  __bf16* qkvb = outwb + 1048576;              // [3][1024][256][64]
  __bf16* attnb = qkvb + (size_t)16384 * 3072; // 16384*1024

  cvt_f32_bf16<<<8192, 256, 0, stream>>>(x, xb, 16777216 / 8);
  cvt_f32_bf16<<<1536, 256, 0, stream>>>(qkv_w, qkvwb, 3145728 / 8);
  cvt_f32_bf16<<<512, 256, 0, stream>>>(out_w, outwb, 1048576 / 8);

  // QKV: M=16384, N=3072, K=1024 -> grid 12 x 64; head-panel output
  gemm256<1><<<dim3(12, 64), 512, 0, stream>>>(xb, qkvwb, qkv_b, qkvb,
                                               16384, 3072, 1024);

  attn_kernel<<<dim3(16, 64), 256, 0, stream>>>(qkvb, attnb);

  // out-proj: M=16384, N=1024, K=1024 -> grid 4 x 64; fp32 row-major out
  gemm256<0><<<dim3(4, 64), 512, 0, stream>>>(attnb, outwb, out_b, out,
                                              16384, 1024, 1024);
}